// Round 1
// baseline (841.135 us; speedup 1.0000x reference)
//
#include <hip/hip_runtime.h>
#include <math.h>

#define INP   768
#define INTR  9216
#define HIDD  9984
#define OUTD  9600
#define BATCH 256

typedef short v8s __attribute__((ext_vector_type(8)));
typedef float v4f __attribute__((ext_vector_type(4)));

__device__ __forceinline__ unsigned short f2bf(float f) {
    unsigned int u = __float_as_uint(f);
    unsigned int r = (u + 0x7FFFu + ((u >> 16) & 1u)) >> 16;
    return (unsigned short)r;
}

// hid[b, j] = sum_{k<384} x[b,k] * W1[j,k]   for j < 9216
// Block tile: BM=128 (batch), BN=64 (j), BK=64. Grid (144, 2). 256 threads = 4 waves (2x2).
__global__ __launch_bounds__(256) void gemm_kernel(const float* __restrict__ x,
                                                   const float* __restrict__ W1,
                                                   float* __restrict__ hid) {
    __shared__ __align__(16) unsigned short As[128][72];  // batch-major, +8 pad
    __shared__ __align__(16) unsigned short Bs[64][72];   // j-major, +8 pad

    const int tid  = threadIdx.x;
    const int bj0  = blockIdx.x * 64;
    const int bb0  = blockIdx.y * 128;
    const int lane = tid & 63;
    const int wave = tid >> 6;
    const int wm   = wave & 1;   // batch half (64 rows)
    const int wn   = wave >> 1;  // j half (32 cols)
    const int lm   = lane & 15;
    const int kq   = lane >> 4;

    v4f acc[4][2];
#pragma unroll
    for (int i = 0; i < 4; i++)
#pragma unroll
        for (int j = 0; j < 2; j++) acc[i][j] = (v4f)(0.0f);

    const int rloc = tid >> 4;        // 0..15
    const int c4   = (tid & 15) * 4;  // 0..60

    for (int kt = 0; kt < 384; kt += 64) {
        // stage A (x): 128 rows x 64 cols
#pragma unroll
        for (int p = 0; p < 8; p++) {
            int row = p * 16 + rloc;
            v4f v = *(const v4f*)(x + (size_t)(bb0 + row) * INP + kt + c4);
            unsigned long long pk = (unsigned long long)f2bf(v.x)
                                  | ((unsigned long long)f2bf(v.y) << 16)
                                  | ((unsigned long long)f2bf(v.z) << 32)
                                  | ((unsigned long long)f2bf(v.w) << 48);
            *(unsigned long long*)&As[row][c4] = pk;
        }
        // stage B (W1): 64 rows x 64 cols
#pragma unroll
        for (int p = 0; p < 4; p++) {
            int row = p * 16 + rloc;
            v4f v = *(const v4f*)(W1 + (size_t)(bj0 + row) * INP + kt + c4);
            unsigned long long pk = (unsigned long long)f2bf(v.x)
                                  | ((unsigned long long)f2bf(v.y) << 16)
                                  | ((unsigned long long)f2bf(v.z) << 32)
                                  | ((unsigned long long)f2bf(v.w) << 48);
            *(unsigned long long*)&Bs[row][c4] = pk;
        }
        __syncthreads();

#pragma unroll
        for (int ks = 0; ks < 2; ks++) {
            v8s a[4], b[2];
#pragma unroll
            for (int mi = 0; mi < 4; mi++)
                a[mi] = *(const v8s*)&As[wm * 64 + mi * 16 + lm][ks * 32 + kq * 8];
#pragma unroll
            for (int ni = 0; ni < 2; ni++)
                b[ni] = *(const v8s*)&Bs[wn * 32 + ni * 16 + lm][ks * 32 + kq * 8];
#pragma unroll
            for (int mi = 0; mi < 4; mi++)
#pragma unroll
                for (int ni = 0; ni < 2; ni++)
                    acc[mi][ni] = __builtin_amdgcn_mfma_f32_16x16x32_bf16(
                        a[mi], b[ni], acc[mi][ni], 0, 0, 0);
        }
        __syncthreads();
    }

    // epilogue: C[row=batch=(lane>>4)*4+reg, col=j=lane&15]
#pragma unroll
    for (int mi = 0; mi < 4; mi++) {
#pragma unroll
        for (int ni = 0; ni < 2; ni++) {
#pragma unroll
            for (int reg = 0; reg < 4; reg++) {
                int b  = bb0 + wm * 64 + mi * 16 + kq * 4 + reg;
                int j  = bj0 + wn * 32 + ni * 16 + lm;
                hid[(size_t)b * HIDD + j] = acc[mi][ni][reg];
            }
        }
    }
}

// hid[b, 9216 + t] = x[b, t], t < 768
__global__ __launch_bounds__(256) void copy_kernel(const float* __restrict__ x,
                                                   float* __restrict__ hid) {
    int i = blockIdx.x * 256 + threadIdx.x;  // over 256*192 float4s
    int b = i / 192;
    int q = i - b * 192;
    v4f v = *(const v4f*)(x + (size_t)b * INP + q * 4);
    *(v4f*)(hid + (size_t)b * HIDD + INTR + q * 4) = v;
}

// outp[b, r] = sparse row r of W2_dyn dot hid[b, :]
__global__ __launch_bounds__(256) void stencil_kernel(const float* __restrict__ Beta,
                                                      const float* __restrict__ W2f,
                                                      const float* __restrict__ hid,
                                                      float* __restrict__ outp) {
    const float HPI = 1.57079632679489662f;
    int i = blockIdx.x * 256 + threadIdx.x;  // 256*9600 threads, r fastest
    int b = i / OUTD;
    int r = i - b * OUTD;
    const float* hrow = hid + (size_t)b * HIDD;
    const float* Brow = Beta + (size_t)r * HIDD;
    float val;
    if (r < INTR) {
        int y  = r / 96;
        int xx = r - y * 96;
        int jE = (xx < 95) ? r + 1  : INTR + 288 + y;
        int jS = (y  < 95) ? r + 96 : INTR + 96 + xx;
        int jW = (xx > 0)  ? r - 1  : INTR + 192 + y;
        int jN = (y  > 0)  ? r - 96 : INTR + xx;
        float wE = Brow[jE], wS = Brow[jS], wW = Brow[jW], wN = Brow[jN];
        float cE = atanf(wE) + HPI;
        float cS = atanf(wS) + HPI;
        float cW = (xx > 0) ? wW : (atanf(wW) + HPI);
        float cN = (y  > 0) ? wN : (atanf(wN) + HPI);
        float dg = W2f[(size_t)r * HIDD + r];
        val = cE * hrow[jE] + cS * hrow[jS] + cW * hrow[jW] + cN * hrow[jN] + dg * hrow[r];
    } else {
        int t = r - INTR;
        int ii;
        if      (t < 96)  ii = t;
        else if (t < 192) ii = 9120 + (t - 96);
        else if (t < 288) ii = 96 * (t - 192);
        else              ii = 96 * (t - 288) + 95;
        float w  = Brow[ii];
        float dg = W2f[(size_t)r * HIDD + r];
        val = w * hrow[ii] + dg * hrow[r] + hrow[r + 384];
    }
    outp[(size_t)b * OUTD + r] = val;
}

extern "C" void kernel_launch(void* const* d_in, const int* in_sizes, int n_in,
                              void* d_out, int out_size, void* d_ws, size_t ws_size,
                              hipStream_t stream) {
    const float* x    = (const float*)d_in[0];
    const float* W1   = (const float*)d_in[1];
    const float* Beta = (const float*)d_in[4];
    const float* W2f  = (const float*)d_in[5];
    float* outp = (float*)d_out;
    float* hid  = outp + (size_t)BATCH * OUTD;

    gemm_kernel<<<dim3(144, 2), 256, 0, stream>>>(x, W1, hid);
    copy_kernel<<<192, 256, 0, stream>>>(x, hid);
    stencil_kernel<<<OUTD, 256, 0, stream>>>(Beta, W2f, hid, outp);
}

// Round 2
// 790.181 us; speedup vs baseline: 1.0645x; 1.0645x over previous
//
#include <hip/hip_runtime.h>
#include <math.h>

#define INP   768
#define INTR  9216
#define HIDD  9984
#define OUTD  9600
#define BATCH 256

typedef short v8s __attribute__((ext_vector_type(8)));
typedef float v4f __attribute__((ext_vector_type(4)));

__device__ __forceinline__ unsigned short f2bf(float f) {
    unsigned int u = __float_as_uint(f);
    unsigned int r = (u + 0x7FFFu + ((u >> 16) & 1u)) >> 16;
    return (unsigned short)r;
}

// hid[b, j] = sum_{k<384} x[b,k] * W1[j,k]   for j < 9216
// Block tile: BM=128 (batch), BN=64 (j), BK=64. Grid (144, 2). 256 threads = 4 waves (2x2).
__global__ __launch_bounds__(256) void gemm_kernel(const float* __restrict__ x,
                                                   const float* __restrict__ W1,
                                                   float* __restrict__ hid) {
    __shared__ __align__(16) unsigned short As[128][72];  // batch-major, +8 pad
    __shared__ __align__(16) unsigned short Bs[64][72];   // j-major, +8 pad

    const int tid  = threadIdx.x;
    const int bj0  = blockIdx.x * 64;
    const int bb0  = blockIdx.y * 128;
    const int lane = tid & 63;
    const int wave = tid >> 6;
    const int wm   = wave & 1;   // batch half (64 rows)
    const int wn   = wave >> 1;  // j half (32 cols)
    const int lm   = lane & 15;
    const int kq   = lane >> 4;

    v4f acc[4][2];
#pragma unroll
    for (int i = 0; i < 4; i++)
#pragma unroll
        for (int j = 0; j < 2; j++) acc[i][j] = (v4f)(0.0f);

    const int rloc = tid >> 4;        // 0..15
    const int c4   = (tid & 15) * 4;  // 0..60

    for (int kt = 0; kt < 384; kt += 64) {
        // stage A (x): 128 rows x 64 cols
#pragma unroll
        for (int p = 0; p < 8; p++) {
            int row = p * 16 + rloc;
            v4f v = *(const v4f*)(x + (size_t)(bb0 + row) * INP + kt + c4);
            unsigned long long pk = (unsigned long long)f2bf(v.x)
                                  | ((unsigned long long)f2bf(v.y) << 16)
                                  | ((unsigned long long)f2bf(v.z) << 32)
                                  | ((unsigned long long)f2bf(v.w) << 48);
            *(unsigned long long*)&As[row][c4] = pk;
        }
        // stage B (W1): 64 rows x 64 cols
#pragma unroll
        for (int p = 0; p < 4; p++) {
            int row = p * 16 + rloc;
            v4f v = *(const v4f*)(W1 + (size_t)(bj0 + row) * INP + kt + c4);
            unsigned long long pk = (unsigned long long)f2bf(v.x)
                                  | ((unsigned long long)f2bf(v.y) << 16)
                                  | ((unsigned long long)f2bf(v.z) << 32)
                                  | ((unsigned long long)f2bf(v.w) << 48);
            *(unsigned long long*)&Bs[row][c4] = pk;
        }
        __syncthreads();

#pragma unroll
        for (int ks = 0; ks < 2; ks++) {
            v8s a[4], b[2];
#pragma unroll
            for (int mi = 0; mi < 4; mi++)
                a[mi] = *(const v8s*)&As[wm * 64 + mi * 16 + lm][ks * 32 + kq * 8];
#pragma unroll
            for (int ni = 0; ni < 2; ni++)
                b[ni] = *(const v8s*)&Bs[wn * 32 + ni * 16 + lm][ks * 32 + kq * 8];
#pragma unroll
            for (int mi = 0; mi < 4; mi++)
#pragma unroll
                for (int ni = 0; ni < 2; ni++)
                    acc[mi][ni] = __builtin_amdgcn_mfma_f32_16x16x32_bf16(
                        a[mi], b[ni], acc[mi][ni], 0, 0, 0);
        }
        __syncthreads();
    }

    // epilogue: C[row=batch=(lane>>4)*4+reg, col=j=lane&15]
#pragma unroll
    for (int mi = 0; mi < 4; mi++) {
#pragma unroll
        for (int ni = 0; ni < 2; ni++) {
#pragma unroll
            for (int reg = 0; reg < 4; reg++) {
                int b  = bb0 + wm * 64 + mi * 16 + kq * 4 + reg;
                int j  = bj0 + wn * 32 + ni * 16 + lm;
                hid[(size_t)b * HIDD + j] = acc[mi][ni][reg];
            }
        }
    }
}

// hid[b, 9216 + t] = x[b, t], t < 768
__global__ __launch_bounds__(256) void copy_kernel(const float* __restrict__ x,
                                                   float* __restrict__ hid) {
    int i = blockIdx.x * 256 + threadIdx.x;  // over 256*192 float4s
    int b = i / 192;
    int q = i - b * 192;
    v4f v = *(const v4f*)(x + (size_t)b * INP + q * 4);
    *(v4f*)(hid + (size_t)b * HIDD + INTR + q * 4) = v;
}

// Per-row W2_dyn coefficients -> ws[r][8]: [0]=diag, [1]=cE/w, [2]=cS, [3]=cW, [4]=cN
__global__ __launch_bounds__(256) void coeff_kernel(const float* __restrict__ Beta,
                                                    const float* __restrict__ W2f,
                                                    float* __restrict__ cf) {
    const float HPI = 1.57079632679489662f;
    int r = blockIdx.x * 256 + threadIdx.x;
    if (r >= OUTD) return;
    const float* Brow = Beta + (size_t)r * HIDD;
    float* crow = cf + (size_t)r * 8;
    float dg = W2f[(size_t)r * HIDD + r];
    crow[0] = dg;
    if (r < INTR) {
        int y  = r / 96;
        int xx = r - y * 96;
        int jE = (xx < 95) ? r + 1  : INTR + 288 + y;
        int jS = (y  < 95) ? r + 96 : INTR + 96 + xx;
        int jW = (xx > 0)  ? r - 1  : INTR + 192 + y;
        int jN = (y  > 0)  ? r - 96 : INTR + xx;
        float wE = Brow[jE], wS = Brow[jS], wW = Brow[jW], wN = Brow[jN];
        crow[1] = atanf(wE) + HPI;
        crow[2] = atanf(wS) + HPI;
        crow[3] = (xx > 0) ? wW : (atanf(wW) + HPI);
        crow[4] = (y  > 0) ? wN : (atanf(wN) + HPI);
    } else {
        int t = r - INTR;
        int ii;
        if      (t < 96)  ii = t;
        else if (t < 192) ii = 9120 + (t - 96);
        else if (t < 288) ii = 96 * (t - 192);
        else              ii = 96 * (t - 288) + 95;
        crow[1] = Brow[ii];
        crow[2] = 0.0f;
        crow[3] = 0.0f;
        crow[4] = 0.0f;
    }
}

// outp[b, r] = sparse row r of W2_dyn dot hid[b, :], coefficients precomputed
__global__ __launch_bounds__(256) void stencil_kernel(const float* __restrict__ cf,
                                                      const float* __restrict__ hid,
                                                      float* __restrict__ outp) {
    int i = blockIdx.x * 256 + threadIdx.x;  // 256*9600 threads, r fastest
    int b = i / OUTD;
    int r = i - b * OUTD;
    const float* hrow = hid + (size_t)b * HIDD;
    const v4f c0 = *(const v4f*)(cf + (size_t)r * 8);      // dg, cE, cS, cW
    const float cN = cf[(size_t)r * 8 + 4];
    float val;
    if (r < INTR) {
        int y  = r / 96;
        int xx = r - y * 96;
        int jE = (xx < 95) ? r + 1  : INTR + 288 + y;
        int jS = (y  < 95) ? r + 96 : INTR + 96 + xx;
        int jW = (xx > 0)  ? r - 1  : INTR + 192 + y;
        int jN = (y  > 0)  ? r - 96 : INTR + xx;
        val = c0.y * hrow[jE] + c0.z * hrow[jS] + c0.w * hrow[jW]
            + cN * hrow[jN] + c0.x * hrow[r];
    } else {
        int t = r - INTR;
        int ii;
        if      (t < 96)  ii = t;
        else if (t < 192) ii = 9120 + (t - 96);
        else if (t < 288) ii = 96 * (t - 192);
        else              ii = 96 * (t - 288) + 95;
        val = c0.y * hrow[ii] + c0.x * hrow[r] + hrow[r + 384];
    }
    outp[(size_t)b * OUTD + r] = val;
}

extern "C" void kernel_launch(void* const* d_in, const int* in_sizes, int n_in,
                              void* d_out, int out_size, void* d_ws, size_t ws_size,
                              hipStream_t stream) {
    const float* x    = (const float*)d_in[0];
    const float* W1   = (const float*)d_in[1];
    const float* Beta = (const float*)d_in[4];
    const float* W2f  = (const float*)d_in[5];
    float* outp = (float*)d_out;
    float* hid  = outp + (size_t)BATCH * OUTD;
    float* cf   = (float*)d_ws;  // 9600 * 8 floats = 307 KB

    coeff_kernel<<<(OUTD + 255) / 256, 256, 0, stream>>>(Beta, W2f, cf);
    gemm_kernel<<<dim3(144, 2), 256, 0, stream>>>(x, W1, hid);
    copy_kernel<<<192, 256, 0, stream>>>(x, hid);
    stencil_kernel<<<OUTD, 256, 0, stream>>>(cf, hid, outp);
}

// Round 3
// 775.149 us; speedup vs baseline: 1.0851x; 1.0194x over previous
//
#include <hip/hip_runtime.h>
#include <math.h>

#define INP   768
#define INTR  9216
#define HIDD  9984
#define OUTD  9600
#define BATCH 256

// prep_kernel block ranges
#define GEMM_BLKS  288   // (144 j-tiles) x (2 batch-tiles)
#define COEFF_BLKS 38    // ceil(9600/256)
#define COPY_BLKS  192   // 256*192 float4s

typedef short v8s __attribute__((ext_vector_type(8)));
typedef float v4f __attribute__((ext_vector_type(4)));

__device__ __forceinline__ unsigned short f2bf(float f) {
    unsigned int u = __float_as_uint(f);
    unsigned int r = (u + 0x7FFFu + ((u >> 16) & 1u)) >> 16;
    return (unsigned short)r;
}

// Fused: gemm (blocks 0..287) + coeff (288..325) + copy (326..517).
// All three are independent; branches are block-uniform.
__global__ __launch_bounds__(256) void prep_kernel(const float* __restrict__ x,
                                                   const float* __restrict__ W1,
                                                   const float* __restrict__ Beta,
                                                   const float* __restrict__ W2f,
                                                   float* __restrict__ hid,
                                                   float* __restrict__ cf) {
    __shared__ __align__(16) unsigned short As[128][72];  // batch-major, +8 pad
    __shared__ __align__(16) unsigned short Bs[64][72];   // j-major, +8 pad

    const int blk = blockIdx.x;
    const int tid = threadIdx.x;

    if (blk < GEMM_BLKS) {
        // ---- GEMM: hid[b, j] = sum_{k<384} x[b,k] * W1[j,k], j < 9216 ----
        // BM=128 (batch), BN=64 (j), BK=64. 4 waves (2x2).
        const int bj0  = (blk % 144) * 64;
        const int bb0  = (blk / 144) * 128;
        const int lane = tid & 63;
        const int wave = tid >> 6;
        const int wm   = wave & 1;
        const int wn   = wave >> 1;
        const int lm   = lane & 15;
        const int kq   = lane >> 4;

        v4f acc[4][2];
#pragma unroll
        for (int i = 0; i < 4; i++)
#pragma unroll
            for (int j = 0; j < 2; j++) acc[i][j] = (v4f)(0.0f);

        const int rloc = tid >> 4;
        const int c4   = (tid & 15) * 4;

        for (int kt = 0; kt < 384; kt += 64) {
#pragma unroll
            for (int p = 0; p < 8; p++) {
                int row = p * 16 + rloc;
                v4f v = *(const v4f*)(x + (size_t)(bb0 + row) * INP + kt + c4);
                unsigned long long pk = (unsigned long long)f2bf(v.x)
                                      | ((unsigned long long)f2bf(v.y) << 16)
                                      | ((unsigned long long)f2bf(v.z) << 32)
                                      | ((unsigned long long)f2bf(v.w) << 48);
                *(unsigned long long*)&As[row][c4] = pk;
            }
#pragma unroll
            for (int p = 0; p < 4; p++) {
                int row = p * 16 + rloc;
                v4f v = *(const v4f*)(W1 + (size_t)(bj0 + row) * INP + kt + c4);
                unsigned long long pk = (unsigned long long)f2bf(v.x)
                                      | ((unsigned long long)f2bf(v.y) << 16)
                                      | ((unsigned long long)f2bf(v.z) << 32)
                                      | ((unsigned long long)f2bf(v.w) << 48);
                *(unsigned long long*)&Bs[row][c4] = pk;
            }
            __syncthreads();

#pragma unroll
            for (int ks = 0; ks < 2; ks++) {
                v8s a[4], b[2];
#pragma unroll
                for (int mi = 0; mi < 4; mi++)
                    a[mi] = *(const v8s*)&As[wm * 64 + mi * 16 + lm][ks * 32 + kq * 8];
#pragma unroll
                for (int ni = 0; ni < 2; ni++)
                    b[ni] = *(const v8s*)&Bs[wn * 32 + ni * 16 + lm][ks * 32 + kq * 8];
#pragma unroll
                for (int mi = 0; mi < 4; mi++)
#pragma unroll
                    for (int ni = 0; ni < 2; ni++)
                        acc[mi][ni] = __builtin_amdgcn_mfma_f32_16x16x32_bf16(
                            a[mi], b[ni], acc[mi][ni], 0, 0, 0);
            }
            __syncthreads();
        }

        // epilogue: C[row=batch=(lane>>4)*4+reg, col=j=lane&15]
#pragma unroll
        for (int mi = 0; mi < 4; mi++) {
#pragma unroll
            for (int ni = 0; ni < 2; ni++) {
#pragma unroll
                for (int reg = 0; reg < 4; reg++) {
                    int b  = bb0 + wm * 64 + mi * 16 + kq * 4 + reg;
                    int j  = bj0 + wn * 32 + ni * 16 + lm;
                    hid[(size_t)b * HIDD + j] = acc[mi][ni][reg];
                }
            }
        }
    } else if (blk < GEMM_BLKS + COEFF_BLKS) {
        // ---- coeff: cf[r][0..4] = diag, cE, cS, cW, cN ----
        const float HPI = 1.57079632679489662f;
        int r = (blk - GEMM_BLKS) * 256 + tid;
        if (r >= OUTD) return;
        const float* Brow = Beta + (size_t)r * HIDD;
        float* crow = cf + (size_t)r * 8;
        crow[0] = W2f[(size_t)r * HIDD + r];
        if (r < INTR) {
            int y  = r / 96;
            int xx = r - y * 96;
            int jE = (xx < 95) ? r + 1  : INTR + 288 + y;
            int jS = (y  < 95) ? r + 96 : INTR + 96 + xx;
            int jW = (xx > 0)  ? r - 1  : INTR + 192 + y;
            int jN = (y  > 0)  ? r - 96 : INTR + xx;
            float wE = Brow[jE], wS = Brow[jS], wW = Brow[jW], wN = Brow[jN];
            crow[1] = atanf(wE) + HPI;
            crow[2] = atanf(wS) + HPI;
            crow[3] = (xx > 0) ? wW : (atanf(wW) + HPI);
            crow[4] = (y  > 0) ? wN : (atanf(wN) + HPI);
        } else {
            int t = r - INTR;
            int ii;
            if      (t < 96)  ii = t;
            else if (t < 192) ii = 9120 + (t - 96);
            else if (t < 288) ii = 96 * (t - 192);
            else              ii = 96 * (t - 288) + 95;
            crow[1] = Brow[ii];
            crow[2] = 0.0f;
            crow[3] = 0.0f;
            crow[4] = 0.0f;
        }
    } else {
        // ---- copy: hid[b, 9216 + t] = x[b, t] ----
        int i = (blk - GEMM_BLKS - COEFF_BLKS) * 256 + tid;
        int b = i / 192;
        int q = i - b * 192;
        v4f v = *(const v4f*)(x + (size_t)b * INP + q * 4);
        *(v4f*)(hid + (size_t)b * HIDD + INTR + q * 4) = v;
    }
}

// outp[b, r] = sparse row r of W2_dyn dot hid[b, :], coefficients precomputed
__global__ __launch_bounds__(256) void stencil_kernel(const float* __restrict__ cf,
                                                      const float* __restrict__ hid,
                                                      float* __restrict__ outp) {
    int i = blockIdx.x * 256 + threadIdx.x;  // 256*9600 threads, r fastest
    int b = i / OUTD;
    int r = i - b * OUTD;
    const float* hrow = hid + (size_t)b * HIDD;
    const v4f c0 = *(const v4f*)(cf + (size_t)r * 8);      // dg, cE, cS, cW
    const float cN = cf[(size_t)r * 8 + 4];
    float val;
    if (r < INTR) {
        int y  = r / 96;
        int xx = r - y * 96;
        int jE = (xx < 95) ? r + 1  : INTR + 288 + y;
        int jS = (y  < 95) ? r + 96 : INTR + 96 + xx;
        int jW = (xx > 0)  ? r - 1  : INTR + 192 + y;
        int jN = (y  > 0)  ? r - 96 : INTR + xx;
        val = c0.y * hrow[jE] + c0.z * hrow[jS] + c0.w * hrow[jW]
            + cN * hrow[jN] + c0.x * hrow[r];
    } else {
        int t = r - INTR;
        int ii;
        if      (t < 96)  ii = t;
        else if (t < 192) ii = 9120 + (t - 96);
        else if (t < 288) ii = 96 * (t - 192);
        else              ii = 96 * (t - 288) + 95;
        val = c0.y * hrow[ii] + c0.x * hrow[r] + hrow[r + 384];
    }
    outp[(size_t)b * OUTD + r] = val;
}

extern "C" void kernel_launch(void* const* d_in, const int* in_sizes, int n_in,
                              void* d_out, int out_size, void* d_ws, size_t ws_size,
                              hipStream_t stream) {
    const float* x    = (const float*)d_in[0];
    const float* W1   = (const float*)d_in[1];
    const float* Beta = (const float*)d_in[4];
    const float* W2f  = (const float*)d_in[5];
    float* outp = (float*)d_out;
    float* hid  = outp + (size_t)BATCH * OUTD;
    float* cf   = (float*)d_ws;  // 9600 * 8 floats = 307 KB

    prep_kernel<<<GEMM_BLKS + COEFF_BLKS + COPY_BLKS, 256, 0, stream>>>(
        x, W1, Beta, W2f, hid, cf);
    stencil_kernel<<<OUTD, 256, 0, stream>>>(cf, hid, outp);
}